// Round 2
// baseline (1182.937 us; speedup 1.0000x reference)
//
#include <hip/hip_runtime.h>
#include <math.h>

namespace {
constexpr int Bn = 8, Cn = 256, Hn = 96, Wn = 128;
constexpr int HWn = Hn * Wn;          // 12288
constexpr int CHWn = Cn * HWn;
constexpr int Kn = 81;
constexpr int TW = 32, TH = 6;        // tile per block
constexpr int HR = TH + 8;            // 14 halo rows
constexpr int HC = TW + 8;            // 40 halo cols
constexpr int HCP = 44;               // padded LDS row stride (floats)
constexpr int CC = 8;                 // channels per LDS chunk
constexpr int NTHREADS = 8 * 9 * 6;   // 432 = tx(8) * g(9) * ty(6)
constexpr int HALO = HR * HC;         // 560
}

__global__ __launch_bounds__(NTHREADS, 4)
void corr81_kernel(const float* __restrict__ fa,
                   const float* __restrict__ fb,
                   float* __restrict__ out) {
  // double-buffered fb tile: 2*8*14*44*4 = 39,424 B (+ssb) -> 2 blocks/CU ok
  __shared__ __align__(16) float lfb[2][CC][HR][HCP];
  __shared__ float ssb[HALO];

  const int tx = threadIdx.x;      // 0..7  column group (4 px each)
  const int g  = threadIdx.y;      // 0..8  == dy
  const int ty = threadIdx.z;      // 0..5  row in tile
  const int tid = tx + 8 * g + 72 * ty;

  // XCD swizzle: id%8 -> XCD; give each XCD one batch image's 64 tiles.
  const int flat = blockIdx.x;
  const int o = (flat & 7) * 64 + (flat >> 3);
  const int b  = o >> 6;
  const int r  = o & 63;
  const int h0 = (r >> 2) * TH;
  const int w0 = (r & 3) * TW;
  const int wb = w0 + 4 * tx;

  // ---- staging geometry: 280 float2 slots; lanes 0..39 of each of the 7
  // waves own 40 slots = exactly 2 halo rows per wave (coalesced loads) ----
  const int lane = tid & 63;
  const int wvi  = tid >> 6;
  const bool s_on = (lane < 40);            // 7*40 = 280 slots
  const int slot = wvi * 40 + lane;         // 0..279
  const int s_hr = slot / 20;               // 20 pair-slots per halo row
  const int s_hc = (slot % 20) * 2;
  const int gh = h0 - 4 + s_hr;
  const int gw = w0 - 4 + s_hc;
  // pairs never straddle validity in w (gw even, Wn even)
  const bool okp = (gh >= 0 && gh < Hn && gw >= 0 && gw + 1 < Wn);
  const float mval = okp ? 1.0f : 0.0f;
  const int ghc = min(max(gh, 0), Hn - 1);
  const int gwc = min(max(gw, 0), Wn - 2);
  const float* sp = fb + (size_t)b * CHWn + (size_t)ghc * Wn + gwc;

  float2 RA[CC], RB[CC];
  float ss0 = 0.0f, ss1 = 0.0f;

  auto loadStage = [&](float2* R, int c0) {
    #pragma unroll
    for (int cc = 0; cc < CC; ++cc)
      R[cc] = *(const float2*)(sp + (size_t)(c0 + cc) * HWn);
  };
  auto writeStage = [&](const float2* R, int buf) {
    #pragma unroll
    for (int cc = 0; cc < CC; ++cc) {
      const float vx = R[cc].x * mval;
      const float vy = R[cc].y * mval;
      ss0 += vx * vx;
      ss1 += vy * vy;
      *(float2*)&lfb[buf][cc][s_hr][s_hc] = make_float2(vx, vy);
    }
  };

  float acc[9][4];
  #pragma unroll
  for (int k = 0; k < 9; ++k) {
    #pragma unroll
    for (int j = 0; j < 4; ++j) acc[k][j] = 0.0f;
  }
  float ssa[4] = {0.f, 0.f, 0.f, 0.f};

  const float* faP = fa + (size_t)b * CHWn + (h0 + ty) * Wn + wb;

  auto loadFa = [&](float4* areg, int c0) {
    #pragma unroll
    for (int cc = 0; cc < CC; ++cc)
      areg[cc] = *(const float4*)(faP + (size_t)(c0 + cc) * HWn);
  };

  auto computeChunk = [&](const float4* areg, const float (*tile)[HR][HCP]) {
    #pragma unroll
    for (int cc = 0; cc < CC; ++cc) {
      const float a0 = areg[cc].x, a1 = areg[cc].y, a2 = areg[cc].z, a3 = areg[cc].w;
      ssa[0] += a0 * a0; ssa[1] += a1 * a1; ssa[2] += a2 * a2; ssa[3] += a3 * a3;
      const float* rowp = &tile[cc][ty + g][4 * tx];
      const float4 wa = *(const float4*)(rowp);
      const float4 wm = *(const float4*)(rowp + 4);
      const float4 wc = *(const float4*)(rowp + 8);
      const float win[12] = {wa.x, wa.y, wa.z, wa.w,
                             wm.x, wm.y, wm.z, wm.w,
                             wc.x, wc.y, wc.z, wc.w};
      #pragma unroll
      for (int dx = 0; dx < 9; ++dx) {
        acc[dx][0] += a0 * win[dx + 0];
        acc[dx][1] += a1 * win[dx + 1];
        acc[dx][2] += a2 * win[dx + 2];
        acc[dx][3] += a3 * win[dx + 3];
      }
    }
  };

  // ---- prologue: prefetch first two chunks into registers ----
  if (s_on) {
    loadStage(RA, 0);
    loadStage(RB, CC);
  }

  // ---- main loop: 1 barrier per chunk, staging prefetched 2 chunks ahead ----
  for (int c0 = 0; c0 < Cn; c0 += 2 * CC) {
    // phase A: chunk c0 via buf0
    float4 aregA[CC];
    loadFa(aregA, c0);                       // issued early, consumed post-bar
    if (s_on) {
      writeStage(RA, 0);
      if (c0 + 2 * CC < Cn) loadStage(RA, c0 + 2 * CC);
    }
    __syncthreads();                         // buf0 ready; buf1 free
    computeChunk(aregA, lfb[0]);

    // phase B: chunk c0+CC via buf1
    float4 aregB[CC];
    loadFa(aregB, c0 + CC);
    if (s_on) {
      writeStage(RB, 1);
      if (c0 + 3 * CC < Cn) loadStage(RB, c0 + 3 * CC);
    }
    __syncthreads();                         // buf1 ready; buf0 free
    computeChunk(aregB, lfb[1]);
  }

  // ---- epilogue: fb rnorm (register sums -> one LDS write), fa rnorm ----
  if (s_on) {
    ssb[s_hr * HC + s_hc]     = 1.0f / fmaxf(sqrtf(ss0), 1e-12f);
    ssb[s_hr * HC + s_hc + 1] = 1.0f / fmaxf(sqrtf(ss1), 1e-12f);
  }
  float rna[4];
  #pragma unroll
  for (int j = 0; j < 4; ++j) rna[j] = 1.0f / fmaxf(sqrtf(ssa[j]), 1e-12f);
  __syncthreads();

  float* outP = out + (size_t)b * (Kn * HWn) + (h0 + ty) * Wn + wb;
  const int rr = ty + g;             // halo row of fb pixel for dy=g
  #pragma unroll
  for (int dx = 0; dx < 9; ++dx) {
    const int k = g * 9 + dx;
    float4 v;
    v.x = acc[dx][0] * rna[0] * ssb[rr * HC + 4 * tx + dx + 0];
    v.y = acc[dx][1] * rna[1] * ssb[rr * HC + 4 * tx + dx + 1];
    v.z = acc[dx][2] * rna[2] * ssb[rr * HC + 4 * tx + dx + 2];
    v.w = acc[dx][3] * rna[3] * ssb[rr * HC + 4 * tx + dx + 3];
    *(float4*)(outP + (size_t)k * HWn) = v;
  }
}

extern "C" void kernel_launch(void* const* d_in, const int* in_sizes, int n_in,
                              void* d_out, int out_size, void* d_ws, size_t ws_size,
                              hipStream_t stream) {
  const float* fa = (const float*)d_in[0];
  const float* fb = (const float*)d_in[1];
  float* outp = (float*)d_out;
  dim3 grid(512);        // 8 b * 16 h-tiles * 4 w-tiles -> exactly 2 blocks/CU
  dim3 block(8, 9, 6);   // 432 threads
  hipLaunchKernelGGL(corr81_kernel, grid, block, 0, stream, fa, fb, outp);
}

// Round 3
// 508.027 us; speedup vs baseline: 2.3285x; 2.3285x over previous
//
#include <hip/hip_runtime.h>
#include <math.h>

namespace {
constexpr int Bn = 8, Cn = 256, Hn = 96, Wn = 128;
constexpr int HWn = Hn * Wn;          // 12288
constexpr int CHWn = Cn * HWn;
constexpr int Kn = 81;
constexpr int TW = 32, TH = 6;        // tile per block
constexpr int HR = TH + 8;            // 14 halo rows
constexpr int HC = TW + 8;            // 40 halo cols
constexpr int HCP = 44;               // padded LDS row stride (floats)
constexpr int CC = 8;                 // channels per LDS chunk
constexpr int NCHUNK = Cn / CC;       // 32
constexpr int NTHREADS = 8 * 9 * 6;   // 432 = tx(8) * g(9) * ty(6)
constexpr int HALO = HR * HC;         // 560
}

__global__ __launch_bounds__(NTHREADS, 4)
void corr81_kernel(const float* __restrict__ fa,
                   const float* __restrict__ fb,
                   float* __restrict__ out) {
  // double-buffered fb tile: 2*8*14*44*4 = 39,424 B (+ssb) -> 2 blocks/CU
  __shared__ __align__(16) float lfb[2][CC][HR][HCP];
  __shared__ float ssb[HALO];

  const int tx = threadIdx.x;      // 0..7  column group (4 px each)
  const int g  = threadIdx.y;      // 0..8  == dy
  const int ty = threadIdx.z;      // 0..5  row in tile
  const int tid = tx + 8 * g + 72 * ty;

  // XCD swizzle: id%8 -> XCD; give each XCD one batch image's 64 tiles.
  const int flat = blockIdx.x;
  const int o = (flat & 7) * 64 + (flat >> 3);
  const int b  = o >> 6;
  const int r  = o & 63;
  const int h0 = (r >> 2) * TH;
  const int w0 = (r & 3) * TW;
  const int wb = w0 + 4 * tx;

  // ---- staging geometry: 280 float2 slots; lanes 0..39 of each of the 7
  // waves own 40 slots = exactly 2 halo rows per wave (coalesced loads) ----
  const int lane = tid & 63;
  const int wvi  = tid >> 6;
  const bool s_on = (lane < 40);            // 7*40 = 280 slots
  const int slot = wvi * 40 + lane;         // 0..279
  const int s_hr = slot / 20;               // 20 pair-slots per halo row
  const int s_hc = (slot % 20) * 2;
  const int gh = h0 - 4 + s_hr;
  const int gw = w0 - 4 + s_hc;
  // pairs never straddle validity in w (gw even, Wn even)
  const bool okp = (gh >= 0 && gh < Hn && gw >= 0 && gw + 1 < Wn);
  const float mval = okp ? 1.0f : 0.0f;
  const int ghc = min(max(gh, 0), Hn - 1);
  const int gwc = min(max(gw, 0), Wn - 2);
  const float* sp = fb + (size_t)b * CHWn + (size_t)ghc * Wn + gwc;

  // single 1-deep staging register set: 16 VGPRs (round-1's 2-deep x
  // {RA,RB,aregA,aregB} blew the 128-VGPR cap from launch_bounds(432,4)
  // and spilled 2.2 GB to scratch)
  float2 R[CC];
  float ss0 = 0.0f, ss1 = 0.0f;

  auto loadStage = [&](int c0) {
    #pragma unroll
    for (int cc = 0; cc < CC; ++cc)
      R[cc] = *(const float2*)(sp + (size_t)(c0 + cc) * HWn);
  };
  auto writeStage = [&](int buf) {
    #pragma unroll
    for (int cc = 0; cc < CC; ++cc) {
      const float vx = R[cc].x * mval;
      const float vy = R[cc].y * mval;
      ss0 += vx * vx;
      ss1 += vy * vy;
      *(float2*)&lfb[buf][cc][s_hr][s_hc] = make_float2(vx, vy);
    }
  };

  float acc[9][4];
  #pragma unroll
  for (int k = 0; k < 9; ++k) {
    #pragma unroll
    for (int j = 0; j < 4; ++j) acc[k][j] = 0.0f;
  }
  float ssa[4] = {0.f, 0.f, 0.f, 0.f};

  const float* faP = fa + (size_t)b * CHWn + (h0 + ty) * Wn + wb;

  // ---- prologue: prefetch chunk 0 into registers ----
  if (s_on) loadStage(0);

  // ---- main loop: 1 barrier per chunk, fb staged 1 chunk ahead in regs ----
  for (int k = 0; k < NCHUNK; ++k) {
    const int buf = k & 1;
    const int c0 = k * CC;
    if (s_on) {
      writeStage(buf);                       // LDS writes for chunk k
      if (k + 1 < NCHUNK) loadStage(c0 + CC); // issue loads for chunk k+1
    }
    // fa prefetch (issued before barrier, consumed after; L1-served
    // across the 9 g-groups sharing each address)
    float4 areg[CC];
    #pragma unroll
    for (int cc = 0; cc < CC; ++cc)
      areg[cc] = *(const float4*)(faP + (size_t)(c0 + cc) * HWn);
    __syncthreads();                         // lfb[buf] ready

    #pragma unroll
    for (int cc = 0; cc < CC; ++cc) {
      const float a0 = areg[cc].x, a1 = areg[cc].y, a2 = areg[cc].z, a3 = areg[cc].w;
      ssa[0] += a0 * a0; ssa[1] += a1 * a1; ssa[2] += a2 * a2; ssa[3] += a3 * a3;
      const float* rowp = &lfb[buf][cc][ty + g][4 * tx];
      const float4 wa = *(const float4*)(rowp);
      const float4 wm = *(const float4*)(rowp + 4);
      const float4 wc = *(const float4*)(rowp + 8);
      const float win[12] = {wa.x, wa.y, wa.z, wa.w,
                             wm.x, wm.y, wm.z, wm.w,
                             wc.x, wc.y, wc.z, wc.w};
      #pragma unroll
      for (int dx = 0; dx < 9; ++dx) {
        acc[dx][0] += a0 * win[dx + 0];
        acc[dx][1] += a1 * win[dx + 1];
        acc[dx][2] += a2 * win[dx + 2];
        acc[dx][3] += a3 * win[dx + 3];
      }
    }
    // no trailing barrier: next iter writes the OTHER buffer; reuse of this
    // buffer is separated by the next iteration's __syncthreads
  }

  // ---- epilogue: fb rnorm (register sums -> one LDS write), fa rnorm ----
  if (s_on) {
    ssb[s_hr * HC + s_hc]     = 1.0f / fmaxf(sqrtf(ss0), 1e-12f);
    ssb[s_hr * HC + s_hc + 1] = 1.0f / fmaxf(sqrtf(ss1), 1e-12f);
  }
  float rna[4];
  #pragma unroll
  for (int j = 0; j < 4; ++j) rna[j] = 1.0f / fmaxf(sqrtf(ssa[j]), 1e-12f);
  __syncthreads();

  float* outP = out + (size_t)b * (Kn * HWn) + (h0 + ty) * Wn + wb;
  const int rr = ty + g;             // halo row of fb pixel for dy=g
  #pragma unroll
  for (int dx = 0; dx < 9; ++dx) {
    const int k = g * 9 + dx;
    float4 v;
    v.x = acc[dx][0] * rna[0] * ssb[rr * HC + 4 * tx + dx + 0];
    v.y = acc[dx][1] * rna[1] * ssb[rr * HC + 4 * tx + dx + 1];
    v.z = acc[dx][2] * rna[2] * ssb[rr * HC + 4 * tx + dx + 2];
    v.w = acc[dx][3] * rna[3] * ssb[rr * HC + 4 * tx + dx + 3];
    *(float4*)(outP + (size_t)k * HWn) = v;
  }
}

extern "C" void kernel_launch(void* const* d_in, const int* in_sizes, int n_in,
                              void* d_out, int out_size, void* d_ws, size_t ws_size,
                              hipStream_t stream) {
  const float* fa = (const float*)d_in[0];
  const float* fb = (const float*)d_in[1];
  float* outp = (float*)d_out;
  dim3 grid(512);        // 8 b * 16 h-tiles * 4 w-tiles -> exactly 2 blocks/CU
  dim3 block(8, 9, 6);   // 432 threads
  hipLaunchKernelGGL(corr81_kernel, grid, block, 0, stream, fa, fb, outp);
}

// Round 4
// 283.717 us; speedup vs baseline: 4.1694x; 1.7906x over previous
//
#include <hip/hip_runtime.h>
#include <math.h>

namespace {
constexpr int Bn = 8, Cn = 256, Hn = 96, Wn = 128;
constexpr int HWn = Hn * Wn;          // 12288
constexpr int CHWn = Cn * HWn;
constexpr int Kn = 81;
constexpr int TW = 32, TH = 6;        // tile per block
constexpr int HR = TH + 8;            // 14 halo rows
constexpr int HC = TW + 8;            // 40 halo cols
constexpr int HCP = 44;               // padded LDS row stride (floats)
constexpr int CC = 8;                 // channels per LDS chunk
constexpr int NCHUNK = Cn / CC;       // 32
constexpr int NTHREADS = 8 * 9 * 6;   // 432 = tx(8) * g(9) * ty(6)
constexpr int HALO = HR * HC;         // 560
}

// launch_bounds min-waves=2 (NOT 4): with 7-wave blocks, min-waves=4 forces the
// allocator to target 6 waves/SIMD -> 64-VGPR clamp -> 360 MB of scratch spill
// (rounds 2-3: VGPR_Count=64, WRITE_SIZE 390 MB vs 31 MB output). min-waves=2
// caps at 256 VGPR; the pipeline needs ~100-128 and we keep 2 blocks/CU.
__global__ __launch_bounds__(NTHREADS, 2)
void corr81_kernel(const float* __restrict__ fa,
                   const float* __restrict__ fb,
                   float* __restrict__ out) {
  // double-buffered fb tile: 2*8*14*44*4 = 39,424 B (+ssb) -> 2 blocks/CU
  __shared__ __align__(16) float lfb[2][CC][HR][HCP];
  __shared__ float ssb[HALO];

  const int tx = threadIdx.x;      // 0..7  column group (4 px each)
  const int g  = threadIdx.y;      // 0..8  == dy
  const int ty = threadIdx.z;      // 0..5  row in tile
  const int tid = tx + 8 * g + 72 * ty;

  // XCD swizzle: id%8 -> XCD; give each XCD one batch image's 64 tiles.
  const int flat = blockIdx.x;
  const int o = (flat & 7) * 64 + (flat >> 3);
  const int b  = o >> 6;
  const int r  = o & 63;
  const int h0 = (r >> 2) * TH;
  const int w0 = (r & 3) * TW;
  const int wb = w0 + 4 * tx;

  // ---- staging geometry: 280 float2 slots; lanes 0..39 of each of the 7
  // waves own 40 slots = exactly 2 halo rows per wave (coalesced loads) ----
  const int lane = tid & 63;
  const int wvi  = tid >> 6;
  const bool s_on = (lane < 40);            // 7*40 = 280 slots
  const int slot = wvi * 40 + lane;         // 0..279
  const int s_hr = slot / 20;               // 20 pair-slots per halo row
  const int s_hc = (slot % 20) * 2;
  const int gh = h0 - 4 + s_hr;
  const int gw = w0 - 4 + s_hc;
  // pairs never straddle validity in w (gw even, Wn even)
  const bool okp = (gh >= 0 && gh < Hn && gw >= 0 && gw + 1 < Wn);
  const float mval = okp ? 1.0f : 0.0f;
  const int ghc = min(max(gh, 0), Hn - 1);
  const int gwc = min(max(gw, 0), Wn - 2);
  const float* sp = fb + (size_t)b * CHWn + (size_t)ghc * Wn + gwc;

  // 1-deep staging register set: 16 VGPRs
  float2 R[CC];
  float ss0 = 0.0f, ss1 = 0.0f;

  auto loadStage = [&](int c0) {
    #pragma unroll
    for (int cc = 0; cc < CC; ++cc)
      R[cc] = *(const float2*)(sp + (size_t)(c0 + cc) * HWn);
  };
  auto writeStage = [&](int buf) {
    #pragma unroll
    for (int cc = 0; cc < CC; ++cc) {
      const float vx = R[cc].x * mval;
      const float vy = R[cc].y * mval;
      ss0 += vx * vx;
      ss1 += vy * vy;
      *(float2*)&lfb[buf][cc][s_hr][s_hc] = make_float2(vx, vy);
    }
  };

  float acc[9][4];
  #pragma unroll
  for (int k = 0; k < 9; ++k) {
    #pragma unroll
    for (int j = 0; j < 4; ++j) acc[k][j] = 0.0f;
  }
  float ssa[4] = {0.f, 0.f, 0.f, 0.f};

  const float* faP = fa + (size_t)b * CHWn + (h0 + ty) * Wn + wb;

  // ---- prologue: prefetch chunk 0 into registers ----
  if (s_on) loadStage(0);

  // ---- main loop: 1 barrier per chunk, fb staged 1 chunk ahead in regs ----
  for (int k = 0; k < NCHUNK; ++k) {
    const int buf = k & 1;
    const int c0 = k * CC;
    if (s_on) {
      writeStage(buf);                        // LDS writes for chunk k
      if (k + 1 < NCHUNK) loadStage(c0 + CC); // issue loads for chunk k+1
    }
    // fa prefetch (issued before barrier, consumed after; L1-served
    // across the 9 g-groups sharing each address)
    float4 areg[CC];
    #pragma unroll
    for (int cc = 0; cc < CC; ++cc)
      areg[cc] = *(const float4*)(faP + (size_t)(c0 + cc) * HWn);
    __syncthreads();                         // lfb[buf] ready

    #pragma unroll
    for (int cc = 0; cc < CC; ++cc) {
      const float a0 = areg[cc].x, a1 = areg[cc].y, a2 = areg[cc].z, a3 = areg[cc].w;
      ssa[0] += a0 * a0; ssa[1] += a1 * a1; ssa[2] += a2 * a2; ssa[3] += a3 * a3;
      const float* rowp = &lfb[buf][cc][ty + g][4 * tx];
      const float4 wa = *(const float4*)(rowp);
      const float4 wm = *(const float4*)(rowp + 4);
      const float4 wc = *(const float4*)(rowp + 8);
      const float win[12] = {wa.x, wa.y, wa.z, wa.w,
                             wm.x, wm.y, wm.z, wm.w,
                             wc.x, wc.y, wc.z, wc.w};
      #pragma unroll
      for (int dx = 0; dx < 9; ++dx) {
        acc[dx][0] += a0 * win[dx + 0];
        acc[dx][1] += a1 * win[dx + 1];
        acc[dx][2] += a2 * win[dx + 2];
        acc[dx][3] += a3 * win[dx + 3];
      }
    }
    // no trailing barrier: next iter writes the OTHER buffer; reuse of this
    // buffer is separated by the next iteration's __syncthreads
  }

  // ---- epilogue: fb rnorm (register sums -> one LDS write), fa rnorm ----
  if (s_on) {
    ssb[s_hr * HC + s_hc]     = 1.0f / fmaxf(sqrtf(ss0), 1e-12f);
    ssb[s_hr * HC + s_hc + 1] = 1.0f / fmaxf(sqrtf(ss1), 1e-12f);
  }
  float rna[4];
  #pragma unroll
  for (int j = 0; j < 4; ++j) rna[j] = 1.0f / fmaxf(sqrtf(ssa[j]), 1e-12f);
  __syncthreads();

  float* outP = out + (size_t)b * (Kn * HWn) + (h0 + ty) * Wn + wb;
  const int rr = ty + g;             // halo row of fb pixel for dy=g
  #pragma unroll
  for (int dx = 0; dx < 9; ++dx) {
    const int k = g * 9 + dx;
    float4 v;
    v.x = acc[dx][0] * rna[0] * ssb[rr * HC + 4 * tx + dx + 0];
    v.y = acc[dx][1] * rna[1] * ssb[rr * HC + 4 * tx + dx + 1];
    v.z = acc[dx][2] * rna[2] * ssb[rr * HC + 4 * tx + dx + 2];
    v.w = acc[dx][3] * rna[3] * ssb[rr * HC + 4 * tx + dx + 3];
    *(float4*)(outP + (size_t)k * HWn) = v;
  }
}

extern "C" void kernel_launch(void* const* d_in, const int* in_sizes, int n_in,
                              void* d_out, int out_size, void* d_ws, size_t ws_size,
                              hipStream_t stream) {
  const float* fa = (const float*)d_in[0];
  const float* fb = (const float*)d_in[1];
  float* outp = (float*)d_out;
  dim3 grid(512);        // 8 b * 16 h-tiles * 4 w-tiles -> exactly 2 blocks/CU
  dim3 block(8, 9, 6);   // 432 threads
  hipLaunchKernelGGL(corr81_kernel, grid, block, 0, stream, fa, fb, outp);
}

// Round 5
// 269.497 us; speedup vs baseline: 4.3894x; 1.0528x over previous
//
#include <hip/hip_runtime.h>
#include <math.h>

namespace {
constexpr int Bn = 8, Cn = 256, Hn = 96, Wn = 128;
constexpr int HWn = Hn * Wn;          // 12288
constexpr int CHWn = Cn * HWn;
constexpr int Kn = 81;
constexpr int TW = 32, TH = 6;        // tile per block
constexpr int HR = TH + 8;            // 14 halo rows
constexpr int HC = TW + 8;            // 40 halo cols
constexpr int HCP = 44;               // padded LDS row stride (floats)
constexpr int CC = 4;                 // channels per LDS chunk (was 8: 42KB LDS
                                      // halved residency in round 4)
constexpr int NCHUNK = Cn / CC;       // 64
constexpr int NTHREADS = 8 * 9 * 6;   // 432 = tx(8) * g(9) * ty(6)
constexpr int HALO = HR * HC;         // 560
}

// min-waves=2: with 7-wave blocks, min-waves=4 clamps to 64 VGPR -> 360 MB
// scratch spill (rounds 2-3). Pipeline needs ~80 VGPR; cap 256 is safe.
__global__ __launch_bounds__(NTHREADS, 2)
void corr81_kernel(const float* __restrict__ fa,
                   const float* __restrict__ fb,
                   float* __restrict__ out) {
  // double-buffered fb tile: 2*4*14*44*4 = 19,712 B + ssb 2,240 B = 21.9 KB
  // == round-0 footprint that ran 2 blocks/CU (round 4's 42 KB ran only 1).
  __shared__ __align__(16) float lfb[2][CC][HR][HCP];
  __shared__ float ssb[HALO];

  const int tx = threadIdx.x;      // 0..7  column group (4 px each)
  const int g  = threadIdx.y;      // 0..8  == dy
  const int ty = threadIdx.z;      // 0..5  row in tile
  const int tid = tx + 8 * g + 72 * ty;

  // XCD swizzle: id%8 -> XCD; give each XCD one batch image's 64 tiles.
  const int flat = blockIdx.x;
  const int o = (flat & 7) * 64 + (flat >> 3);
  const int b  = o >> 6;
  const int r  = o & 63;
  const int h0 = (r >> 2) * TH;
  const int w0 = (r & 3) * TW;
  const int wb = w0 + 4 * tx;

  // ---- staging geometry: 280 float2 slots; lanes 0..39 of each of the 7
  // waves own 40 slots = exactly 2 halo rows per wave (coalesced loads) ----
  const int lane = tid & 63;
  const int wvi  = tid >> 6;
  const bool s_on = (lane < 40);            // 7*40 = 280 slots
  const int slot = wvi * 40 + lane;         // 0..279
  const int s_hr = slot / 20;               // 20 pair-slots per halo row
  const int s_hc = (slot % 20) * 2;
  const int gh = h0 - 4 + s_hr;
  const int gw = w0 - 4 + s_hc;
  // pairs never straddle validity in w (gw even, Wn even)
  const bool okp = (gh >= 0 && gh < Hn && gw >= 0 && gw + 1 < Wn);
  const float mval = okp ? 1.0f : 0.0f;
  const int ghc = min(max(gh, 0), Hn - 1);
  const int gwc = min(max(gw, 0), Wn - 2);
  const float* sp = fb + (size_t)b * CHWn + (size_t)ghc * Wn + gwc;

  // 1-deep staging register set: 8 VGPRs
  float2 R[CC];
  float ss0 = 0.0f, ss1 = 0.0f;

  auto loadStage = [&](int c0) {
    #pragma unroll
    for (int cc = 0; cc < CC; ++cc)
      R[cc] = *(const float2*)(sp + (size_t)(c0 + cc) * HWn);
  };
  auto writeStage = [&](int buf) {
    #pragma unroll
    for (int cc = 0; cc < CC; ++cc) {
      const float vx = R[cc].x * mval;
      const float vy = R[cc].y * mval;
      ss0 += vx * vx;
      ss1 += vy * vy;
      *(float2*)&lfb[buf][cc][s_hr][s_hc] = make_float2(vx, vy);
    }
  };

  float acc[9][4];
  #pragma unroll
  for (int k = 0; k < 9; ++k) {
    #pragma unroll
    for (int j = 0; j < 4; ++j) acc[k][j] = 0.0f;
  }
  float ssa[4] = {0.f, 0.f, 0.f, 0.f};

  const float* faP = fa + (size_t)b * CHWn + (h0 + ty) * Wn + wb;

  // ---- prologue: prefetch chunk 0 into registers ----
  if (s_on) loadStage(0);

  // ---- main loop: 1 barrier per chunk, fb staged 1 chunk ahead in regs ----
  for (int k = 0; k < NCHUNK; ++k) {
    const int buf = k & 1;
    const int c0 = k * CC;
    // fa prefetch first: independent global loads, issued earliest
    float4 areg[CC];
    #pragma unroll
    for (int cc = 0; cc < CC; ++cc)
      areg[cc] = *(const float4*)(faP + (size_t)(c0 + cc) * HWn);
    if (s_on) {
      writeStage(buf);                        // LDS writes for chunk k
      if (k + 1 < NCHUNK) loadStage(c0 + CC); // issue loads for chunk k+1
    }
    __syncthreads();                          // lfb[buf] ready

    #pragma unroll
    for (int cc = 0; cc < CC; ++cc) {
      const float a0 = areg[cc].x, a1 = areg[cc].y, a2 = areg[cc].z, a3 = areg[cc].w;
      ssa[0] += a0 * a0; ssa[1] += a1 * a1; ssa[2] += a2 * a2; ssa[3] += a3 * a3;
      const float* rowp = &lfb[buf][cc][ty + g][4 * tx];
      const float4 wa = *(const float4*)(rowp);
      const float4 wm = *(const float4*)(rowp + 4);
      const float4 wc = *(const float4*)(rowp + 8);
      const float win[12] = {wa.x, wa.y, wa.z, wa.w,
                             wm.x, wm.y, wm.z, wm.w,
                             wc.x, wc.y, wc.z, wc.w};
      #pragma unroll
      for (int dx = 0; dx < 9; ++dx) {
        acc[dx][0] += a0 * win[dx + 0];
        acc[dx][1] += a1 * win[dx + 1];
        acc[dx][2] += a2 * win[dx + 2];
        acc[dx][3] += a3 * win[dx + 3];
      }
    }
    // no trailing barrier: next iter writes the OTHER buffer; a wave's reads
    // of this buffer are drained by the lgkmcnt(0) before the NEXT barrier,
    // which precedes any re-write of this buffer (k+2).
  }

  // ---- epilogue: fb rnorm (register sums -> one LDS write), fa rnorm ----
  if (s_on) {
    ssb[s_hr * HC + s_hc]     = 1.0f / fmaxf(sqrtf(ss0), 1e-12f);
    ssb[s_hr * HC + s_hc + 1] = 1.0f / fmaxf(sqrtf(ss1), 1e-12f);
  }
  float rna[4];
  #pragma unroll
  for (int j = 0; j < 4; ++j) rna[j] = 1.0f / fmaxf(sqrtf(ssa[j]), 1e-12f);
  __syncthreads();

  float* outP = out + (size_t)b * (Kn * HWn) + (h0 + ty) * Wn + wb;
  const int rr = ty + g;             // halo row of fb pixel for dy=g
  #pragma unroll
  for (int dx = 0; dx < 9; ++dx) {
    const int k = g * 9 + dx;
    float4 v;
    v.x = acc[dx][0] * rna[0] * ssb[rr * HC + 4 * tx + dx + 0];
    v.y = acc[dx][1] * rna[1] * ssb[rr * HC + 4 * tx + dx + 1];
    v.z = acc[dx][2] * rna[2] * ssb[rr * HC + 4 * tx + dx + 2];
    v.w = acc[dx][3] * rna[3] * ssb[rr * HC + 4 * tx + dx + 3];
    *(float4*)(outP + (size_t)k * HWn) = v;
  }
}

extern "C" void kernel_launch(void* const* d_in, const int* in_sizes, int n_in,
                              void* d_out, int out_size, void* d_ws, size_t ws_size,
                              hipStream_t stream) {
  const float* fa = (const float*)d_in[0];
  const float* fb = (const float*)d_in[1];
  float* outp = (float*)d_out;
  dim3 grid(512);        // 8 b * 16 h-tiles * 4 w-tiles -> exactly 2 blocks/CU
  dim3 block(8, 9, 6);   // 432 threads
  hipLaunchKernelGGL(corr81_kernel, grid, block, 0, stream, fa, fb, outp);
}